// Round 3
// baseline (1167.227 us; speedup 1.0000x reference)
//
#include <hip/hip_runtime.h>

#define DM   2048
#define NH   16
#define HD   128
#define QKVN 6144
#define NTOT 2048

typedef __bf16 bf16x8 __attribute__((ext_vector_type(8)));
typedef float  f32x4  __attribute__((ext_vector_type(4)));

__device__ __forceinline__ unsigned short f2bf(float f) {
  union { float f; unsigned u; } v; v.f = f;
  return (unsigned short)((v.u + 0x7FFFu + ((v.u >> 16) & 1u)) >> 16);
}
__device__ __forceinline__ float bf2f(unsigned short u) {
  union { unsigned u; float f; } v; v.u = ((unsigned)u) << 16;
  return v.f;
}

// ---------------------------------------------------------------------------
// GEMM1: X[2048x2048] fp32 @ W[2048x6144] fp32 + bias, fused QKNorm+RoPE,
// scatter to Q/K/V bf16 [b][h][2048][128].  Tile 128x128, BK=32, 4 waves.
// MFMA 16x16x32 bf16: A lane: A[m=l&15][k=(l>>4)*8+j]; B lane: B[k=(l>>4)*8+j][n=l&15];
// C lane reg i: C[row=(l>>4)*4+i][col=l&15]   (verified m89/m91)
// ---------------------------------------------------------------------------
union QkvLds {
  struct { unsigned short a[128][40]; unsigned short b[128][40]; } s;  // 20480 B
  unsigned short c[128][130];                                          // 33280 B
};

__global__ __launch_bounds__(256) void gemm_qkv(
    const float* __restrict__ X, const float* __restrict__ W,
    const float* __restrict__ bias, const float* __restrict__ qg,
    const float* __restrict__ kg,
    unsigned short* __restrict__ Q, unsigned short* __restrict__ K,
    unsigned short* __restrict__ V, int stream_off)
{
  __shared__ __align__(16) QkvLds L;
  const int tid  = threadIdx.x;
  const int lane = tid & 63;
  const int wv   = tid >> 6;
  const int wrow = (wv >> 1) * 64, wcol = (wv & 1) * 64;
  const int quad = lane >> 4, l15 = lane & 15;
  const int m0 = blockIdx.y * 128;
  const int n0 = blockIdx.x * 128;

  f32x4 acc[4][4];
#pragma unroll
  for (int i = 0; i < 4; i++)
#pragma unroll
    for (int j = 0; j < 4; j++) acc[i][j] = (f32x4){0.f, 0.f, 0.f, 0.f};

  for (int k0 = 0; k0 < DM; k0 += 32) {
    // stage A (128x32 fp32 -> bf16), coalesced float4
#pragma unroll
    for (int it = 0; it < 4; ++it) {
      int lin = tid + it * 256;              // 0..1023
      int row = lin >> 3, c4 = (lin & 7) * 4;
      float4 av = *reinterpret_cast<const float4*>(&X[(size_t)(m0 + row) * DM + k0 + c4]);
      ushort4 t4;
      t4.x = f2bf(av.x); t4.y = f2bf(av.y); t4.z = f2bf(av.z); t4.w = f2bf(av.w);
      *reinterpret_cast<ushort4*>(&L.s.a[row][c4]) = t4;
    }
    // stage B (32x128 fp32 -> bf16, transposed into [n][k])
#pragma unroll
    for (int it = 0; it < 4; ++it) {
      int lin = tid + it * 256;
      int kr = lin >> 5, c4 = (lin & 31) * 4;
      float4 wv4 = *reinterpret_cast<const float4*>(&W[(size_t)(k0 + kr) * QKVN + n0 + c4]);
      L.s.b[c4 + 0][kr] = f2bf(wv4.x);
      L.s.b[c4 + 1][kr] = f2bf(wv4.y);
      L.s.b[c4 + 2][kr] = f2bf(wv4.z);
      L.s.b[c4 + 3][kr] = f2bf(wv4.w);
    }
    __syncthreads();
    bf16x8 af[4], bfr[4];
#pragma unroll
    for (int mt = 0; mt < 4; mt++)
      af[mt] = *reinterpret_cast<const bf16x8*>(&L.s.a[wrow + mt * 16 + l15][quad * 8]);
#pragma unroll
    for (int nt = 0; nt < 4; nt++)
      bfr[nt] = *reinterpret_cast<const bf16x8*>(&L.s.b[wcol + nt * 16 + l15][quad * 8]);
#pragma unroll
    for (int mt = 0; mt < 4; mt++)
#pragma unroll
      for (int nt = 0; nt < 4; nt++)
        acc[mt][nt] = __builtin_amdgcn_mfma_f32_16x16x32_bf16(af[mt], bfr[nt], acc[mt][nt], 0, 0, 0);
    __syncthreads();
  }

  // epilogue: bias, round to bf16 into LDS
#pragma unroll
  for (int mt = 0; mt < 4; mt++)
#pragma unroll
    for (int nt = 0; nt < 4; nt++) {
      int col = wcol + nt * 16 + l15;
      float bv = bias[n0 + col];
#pragma unroll
      for (int i = 0; i < 4; i++) {
        int row = wrow + mt * 16 + quad * 4 + i;
        L.c[row][col] = f2bf(acc[mt][nt][i] + bv);
      }
    }
  __syncthreads();

  if (tid < 128) {
    int r = tid;
    int cc = n0 >> 7;           // 0..47
    int t = cc >> 4;            // 0=q 1=k 2=v
    int h = cc & 15;
    int gr = m0 + r;
    int b = gr >> 10, n = gr & 1023;
    int pos = stream_off + n;
    size_t base = ((size_t)(b * NH + h) * NTOT + pos) * HD;
    if (t == 2) {
      for (int j = 0; j < HD; j++) V[base + j] = L.c[r][j];
    } else {
      float ssq = 0.f;
      for (int j = 0; j < HD; j++) { float f = bf2f(L.c[r][j]); ssq += f * f; }
      float inv = rsqrtf(ssq * (1.0f / HD) + 1e-6f);
      const float* g = (t == 0) ? qg : kg;
      unsigned short* dst = (t == 0) ? Q : K;
      for (int j = 0; j < 64; j++) {
        float x1 = bf2f(L.c[r][j])      * inv * g[j];
        float x2 = bf2f(L.c[r][j + 64]) * inv * g[j + 64];
        // inv_freq = 10000^(-j/64) = exp2(-j*log2(10000)/64)
        float ang = (float)pos * exp2f(-(float)j * 0.2076205059304601f);
        float s, c; sincosf(ang, &s, &c);
        dst[base + j]      = f2bf(x1 * c - x2 * s);
        dst[base + j + 64] = f2bf(x1 * s + x2 * c);
      }
    }
  }
}

// ---------------------------------------------------------------------------
// Flash attention: Q-tile 128 (4 waves x 32 rows), K-tile 64, d=128.
// Each wave owns whole score rows -> softmax is 16-lane shuffle only.
// P goes C-layout -> LDS -> A-layout (verified m120 pattern).
// ---------------------------------------------------------------------------
__global__ __launch_bounds__(256) void attn_kernel(
    const unsigned short* __restrict__ Q, const unsigned short* __restrict__ K,
    const unsigned short* __restrict__ V, unsigned short* __restrict__ O)
{
  __shared__ __align__(16) unsigned short Ks[64][136];   // [key][d]
  __shared__ __align__(16) unsigned short Vt[128][72];   // [d][key]
  __shared__ __align__(16) unsigned short Ps[128][72];   // [q][key] per-wave rows

  const int tid  = threadIdx.x;
  const int lane = tid & 63, w = tid >> 6;
  const int quad = lane >> 4, l15 = lane & 15;
  const int b = blockIdx.z, h = blockIdx.y;
  const int q0 = blockIdx.x * 128;
  const size_t base = (size_t)(b * NH + h) * NTOT * HD;
  const float scale = 0.088388347648318447f;  // 1/sqrt(128)

  bf16x8 qf[2][4];
#pragma unroll
  for (int mt = 0; mt < 2; mt++)
#pragma unroll
    for (int ks = 0; ks < 4; ks++)
      qf[mt][ks] = *reinterpret_cast<const bf16x8*>(
          &Q[base + (size_t)(q0 + w * 32 + mt * 16 + l15) * HD + ks * 32 + quad * 8]);

  f32x4 oacc[2][8];
#pragma unroll
  for (int mt = 0; mt < 2; mt++)
#pragma unroll
    for (int nt = 0; nt < 8; nt++) oacc[mt][nt] = (f32x4){0.f, 0.f, 0.f, 0.f};
  float mst[2][4], lst[2][4];
#pragma unroll
  for (int mt = 0; mt < 2; mt++)
#pragma unroll
    for (int i = 0; i < 4; i++) { mst[mt][i] = -1e30f; lst[mt][i] = 0.f; }

  for (int kt = 0; kt < NTOT / 64; ++kt) {
    // stage K [64][128] and V^T [128][64]
#pragma unroll
    for (int it = 0; it < 4; ++it) {
      int lin = tid + it * 256;
      int kr = lin >> 4, c8 = (lin & 15) * 8;
      uint4 kv = *reinterpret_cast<const uint4*>(&K[base + (size_t)(kt * 64 + kr) * HD + c8]);
      *reinterpret_cast<uint4*>(&Ks[kr][c8]) = kv;
      uint4 vv = *reinterpret_cast<const uint4*>(&V[base + (size_t)(kt * 64 + kr) * HD + c8]);
      const unsigned short* vs = reinterpret_cast<const unsigned short*>(&vv);
#pragma unroll
      for (int j = 0; j < 8; j++) Vt[c8 + j][kr] = vs[j];
    }
    __syncthreads();

    // S = Q K^T
    f32x4 sacc[2][4];
#pragma unroll
    for (int mt = 0; mt < 2; mt++)
#pragma unroll
      for (int nt = 0; nt < 4; nt++) sacc[mt][nt] = (f32x4){0.f, 0.f, 0.f, 0.f};
#pragma unroll
    for (int ks = 0; ks < 4; ks++) {
      bf16x8 kf[4];
#pragma unroll
      for (int nt = 0; nt < 4; nt++)
        kf[nt] = *reinterpret_cast<const bf16x8*>(&Ks[nt * 16 + l15][ks * 32 + quad * 8]);
#pragma unroll
      for (int mt = 0; mt < 2; mt++)
#pragma unroll
        for (int nt = 0; nt < 4; nt++)
          sacc[mt][nt] = __builtin_amdgcn_mfma_f32_16x16x32_bf16(qf[mt][ks], kf[nt], sacc[mt][nt], 0, 0, 0);
    }

    // online softmax per (mt,i) row; rows live in 16-lane quad groups
#pragma unroll
    for (int mt = 0; mt < 2; mt++)
#pragma unroll
      for (int i = 0; i < 4; i++) {
        float sv[4];
        float rmax = -1e30f;
#pragma unroll
        for (int nt = 0; nt < 4; nt++) {
          sv[nt] = sacc[mt][nt][i] * scale;
          rmax = fmaxf(rmax, sv[nt]);
        }
        rmax = fmaxf(rmax, __shfl_xor(rmax, 1));
        rmax = fmaxf(rmax, __shfl_xor(rmax, 2));
        rmax = fmaxf(rmax, __shfl_xor(rmax, 4));
        rmax = fmaxf(rmax, __shfl_xor(rmax, 8));
        float mnew  = fmaxf(mst[mt][i], rmax);
        float alpha = __expf(mst[mt][i] - mnew);
        float rsum = 0.f;
#pragma unroll
        for (int nt = 0; nt < 4; nt++) {
          float p = __expf(sv[nt] - mnew);
          rsum += p;
          Ps[w * 32 + mt * 16 + quad * 4 + i][nt * 16 + l15] = f2bf(p);
        }
        rsum += __shfl_xor(rsum, 1);
        rsum += __shfl_xor(rsum, 2);
        rsum += __shfl_xor(rsum, 4);
        rsum += __shfl_xor(rsum, 8);
        lst[mt][i] = lst[mt][i] * alpha + rsum;
        mst[mt][i] = mnew;
#pragma unroll
        for (int nt = 0; nt < 8; nt++) oacc[mt][nt][i] *= alpha;
      }

    // TBAA hazard: Ps written as unsigned short, read as bf16x8 — real barrier
    // prevents the compiler from hoisting the ds_reads above the writes.
    __syncthreads();

    // O += P V
#pragma unroll
    for (int kk = 0; kk < 2; kk++) {
      bf16x8 pf[2];
#pragma unroll
      for (int mt = 0; mt < 2; mt++)
        pf[mt] = *reinterpret_cast<const bf16x8*>(&Ps[w * 32 + mt * 16 + l15][kk * 32 + quad * 8]);
#pragma unroll
      for (int nt = 0; nt < 8; nt++) {
        bf16x8 vf = *reinterpret_cast<const bf16x8*>(&Vt[nt * 16 + l15][kk * 32 + quad * 8]);
#pragma unroll
        for (int mt = 0; mt < 2; mt++)
          oacc[mt][nt] = __builtin_amdgcn_mfma_f32_16x16x32_bf16(pf[mt], vf, oacc[mt][nt], 0, 0, 0);
      }
    }
    __syncthreads();
  }

  // normalize and store to ATT [b][n][h*128] bf16
#pragma unroll
  for (int mt = 0; mt < 2; mt++)
#pragma unroll
    for (int i = 0; i < 4; i++) {
      float linv = 1.0f / lst[mt][i];
      int qrow = q0 + w * 32 + mt * 16 + quad * 4 + i;
      size_t ob = ((size_t)b * NTOT + qrow) * DM + h * HD;
#pragma unroll
      for (int nt = 0; nt < 8; nt++)
        O[ob + nt * 16 + l15] = f2bf(oacc[mt][nt][i] * linv);
    }
}

// ---------------------------------------------------------------------------
// GEMM2: ATT rows (bf16) @ W_out fp32 + bias -> d_out fp32
// ---------------------------------------------------------------------------
__global__ __launch_bounds__(256) void gemm_out(
    const unsigned short* __restrict__ A, const float* __restrict__ W,
    const float* __restrict__ bias, float* __restrict__ Out, int stream_off)
{
  __shared__ __align__(16) struct { unsigned short a[128][40]; unsigned short b[128][40]; } L;
  const int tid  = threadIdx.x;
  const int lane = tid & 63;
  const int wv   = tid >> 6;
  const int wrow = (wv >> 1) * 64, wcol = (wv & 1) * 64;
  const int quad = lane >> 4, l15 = lane & 15;
  const int m0 = blockIdx.y * 128;
  const int n0 = blockIdx.x * 128;

  f32x4 acc[4][4];
#pragma unroll
  for (int i = 0; i < 4; i++)
#pragma unroll
    for (int j = 0; j < 4; j++) acc[i][j] = (f32x4){0.f, 0.f, 0.f, 0.f};

  for (int k0 = 0; k0 < DM; k0 += 32) {
    // stage A (bf16, direct 16B copies)
#pragma unroll
    for (int it = 0; it < 2; ++it) {
      int lin = tid + it * 256;              // 0..511
      int row = lin >> 2, c8 = (lin & 3) * 8;
      int gr = m0 + row;
      int bb = gr >> 10, n = gr & 1023;
      uint4 av = *reinterpret_cast<const uint4*>(
          &A[(size_t)(bb * NTOT + stream_off + n) * DM + k0 + c8]);
      *reinterpret_cast<uint4*>(&L.a[row][c8]) = av;
    }
    // stage B (fp32 -> bf16 transposed)
#pragma unroll
    for (int it = 0; it < 4; ++it) {
      int lin = tid + it * 256;
      int kr = lin >> 5, c4 = (lin & 31) * 4;
      float4 wv4 = *reinterpret_cast<const float4*>(&W[(size_t)(k0 + kr) * DM + n0 + c4]);
      L.b[c4 + 0][kr] = f2bf(wv4.x);
      L.b[c4 + 1][kr] = f2bf(wv4.y);
      L.b[c4 + 2][kr] = f2bf(wv4.z);
      L.b[c4 + 3][kr] = f2bf(wv4.w);
    }
    __syncthreads();
    bf16x8 af[4], bfr[4];
#pragma unroll
    for (int mt = 0; mt < 4; mt++)
      af[mt] = *reinterpret_cast<const bf16x8*>(&L.a[wrow + mt * 16 + l15][quad * 8]);
#pragma unroll
    for (int nt = 0; nt < 4; nt++)
      bfr[nt] = *reinterpret_cast<const bf16x8*>(&L.b[wcol + nt * 16 + l15][quad * 8]);
#pragma unroll
    for (int mt = 0; mt < 4; mt++)
#pragma unroll
      for (int nt = 0; nt < 4; nt++)
        acc[mt][nt] = __builtin_amdgcn_mfma_f32_16x16x32_bf16(af[mt], bfr[nt], acc[mt][nt], 0, 0, 0);
    __syncthreads();
  }

#pragma unroll
  for (int mt = 0; mt < 4; mt++)
#pragma unroll
    for (int nt = 0; nt < 4; nt++) {
      int col = wcol + nt * 16 + l15;
      float bv = bias[n0 + col];
#pragma unroll
      for (int i = 0; i < 4; i++) {
        int row = wrow + mt * 16 + quad * 4 + i;
        Out[(size_t)(m0 + row) * DM + n0 + col] = acc[mt][nt][i] + bv;
      }
    }
}

// ---------------------------------------------------------------------------
extern "C" void kernel_launch(void* const* d_in, const int* in_sizes, int n_in,
                              void* d_out, int out_size, void* d_ws, size_t ws_size,
                              hipStream_t stream) {
  (void)in_sizes; (void)n_in; (void)out_size; (void)ws_size;
  const float* x1  = (const float*)d_in[0];
  const float* x2  = (const float*)d_in[1];
  const float* wq1 = (const float*)d_in[2];
  const float* bq1 = (const float*)d_in[3];
  const float* wq2 = (const float*)d_in[4];
  const float* bq2 = (const float*)d_in[5];
  const float* qg1 = (const float*)d_in[6];
  const float* kg1 = (const float*)d_in[7];
  const float* qg2 = (const float*)d_in[8];
  const float* kg2 = (const float*)d_in[9];
  const float* wo1 = (const float*)d_in[10];
  const float* bo1 = (const float*)d_in[11];
  const float* wo2 = (const float*)d_in[12];
  const float* bo2 = (const float*)d_in[13];

  const size_t QKV_ELEMS = (size_t)2 * NH * NTOT * HD;  // 8388608
  unsigned short* Q   = (unsigned short*)d_ws;
  unsigned short* K   = Q + QKV_ELEMS;
  unsigned short* V   = K + QKV_ELEMS;
  unsigned short* ATT = V + QKV_ELEMS;
  float* out = (float*)d_out;

  dim3 blk(256);
  hipLaunchKernelGGL(gemm_qkv, dim3(48, 16), blk, 0, stream, x1, wq1, bq1, qg1, kg1, Q, K, V, 0);
  hipLaunchKernelGGL(gemm_qkv, dim3(48, 16), blk, 0, stream, x2, wq2, bq2, qg2, kg2, Q, K, V, 1024);
  hipLaunchKernelGGL(attn_kernel, dim3(16, 16, 2), blk, 0, stream, Q, K, V, ATT);
  hipLaunchKernelGGL(gemm_out, dim3(16, 16), blk, 0, stream, ATT, wo1, bo1, out, 0);
  hipLaunchKernelGGL(gemm_out, dim3(16, 16), blk, 0, stream, ATT, wo2, bo2, out + (size_t)2 * 1024 * DM, 1024);
}

// Round 4
// 585.373 us; speedup vs baseline: 1.9940x; 1.9940x over previous
//
#include <hip/hip_runtime.h>

#define DM   2048
#define NH   16
#define HD   128
#define QKVN 6144
#define NTOT 2048

typedef __bf16 bf16x8 __attribute__((ext_vector_type(8)));
typedef float  f32x4  __attribute__((ext_vector_type(4)));
typedef unsigned short ushort_t;

__device__ __forceinline__ unsigned short f2bf(float f) {
  union { float f; unsigned u; } v; v.f = f;
  return (unsigned short)((v.u + 0x7FFFu + ((v.u >> 16) & 1u)) >> 16);
}
__device__ __forceinline__ float bf2f(unsigned short u) {
  union { unsigned u; float f; } v; v.u = ((unsigned)u) << 16;
  return v.f;
}
// async global->LDS, 16B per lane. LDS dest = wave-uniform base + lane*16.
__device__ __forceinline__ void glds16(const void* g, void* l) {
  __builtin_amdgcn_global_load_lds(
      (const __attribute__((address_space(1))) unsigned int*)g,
      (__attribute__((address_space(3))) unsigned int*)l, 16, 0, 0);
}
#define COMPILER_MEM_BARRIER() asm volatile("" ::: "memory")

// ===========================================================================
// FAST PATH
// ===========================================================================

// prep: W transposes fp32[k][n] -> bf16[n][k]; X fp32->bf16; RoPE table.
__global__ __launch_bounds__(256) void prep_kernel(
    const float* __restrict__ wq1, const float* __restrict__ wq2,
    const float* __restrict__ wo1, const float* __restrict__ wo2,
    const float* __restrict__ x1,  const float* __restrict__ x2,
    ushort_t* __restrict__ wq1t, ushort_t* __restrict__ wq2t,
    ushort_t* __restrict__ wo1t, ushort_t* __restrict__ wo2t,
    ushort_t* __restrict__ xb1,  ushort_t* __restrict__ xb2,
    float2* __restrict__ rtab)
{
  __shared__ __align__(16) unsigned short Ls[64][72];
  const int bid = blockIdx.x, tid = threadIdx.x;
  if (bid < 8192) {
    const float* src; ushort_t* dst; int N, nb, kb;
    if (bid < 6144) {
      src = (bid < 3072) ? wq1 : wq2; dst = (bid < 3072) ? wq1t : wq2t;
      int id = bid % 3072; N = QKVN; nb = id % 96; kb = id / 96;
    } else {
      int id = bid - 6144;
      src = (id < 1024) ? wo1 : wo2; dst = (id < 1024) ? wo1t : wo2t;
      id %= 1024; N = DM; nb = id % 32; kb = id / 32;
    }
    int n0 = nb * 64, k0 = kb * 64;
#pragma unroll
    for (int it = 0; it < 4; ++it) {
      int row = (tid >> 4) + it * 16, c4 = (tid & 15) * 4;
      float4 v = *reinterpret_cast<const float4*>(&src[(size_t)(k0 + row) * N + n0 + c4]);
      Ls[c4 + 0][row] = f2bf(v.x); Ls[c4 + 1][row] = f2bf(v.y);
      Ls[c4 + 2][row] = f2bf(v.z); Ls[c4 + 3][row] = f2bf(v.w);
    }
    __syncthreads();
#pragma unroll
    for (int it = 0; it < 2; ++it) {
      int lin = tid + it * 256, r = lin >> 3, c8 = (lin & 7) * 8;
      *reinterpret_cast<uint4*>(&dst[(size_t)(n0 + r) * 2048 + k0 + c8]) =
          *reinterpret_cast<const uint4*>(&Ls[r][c8]);
    }
  } else if (bid < 10240) {
    int id = bid - 8192;
    const float* src = (id < 1024) ? x1 : x2;
    ushort_t* dst = (id < 1024) ? xb1 : xb2;
    id %= 1024;
    size_t base = (size_t)id * 4096;
#pragma unroll
    for (int it = 0; it < 4; ++it) {
      size_t i = base + (size_t)(it * 256 + tid) * 4;
      float4 v = *reinterpret_cast<const float4*>(&src[i]);
      ushort4 t; t.x = f2bf(v.x); t.y = f2bf(v.y); t.z = f2bf(v.z); t.w = f2bf(v.w);
      *reinterpret_cast<ushort4*>(&dst[i]) = t;
    }
  } else {
    int id = bid - 10240;
    int e0 = id * 16384;
    for (int i = tid; i < 16384; i += 256) {
      int e = e0 + i; int pos = e >> 6, j = e & 63;
      float ang = (float)pos * exp2f(-(float)j * 0.2076205059304601f);
      float s, c; sincosf(ang, &s, &c);
      rtab[e] = make_float2(c, s);
    }
  }
}

// GEMM1 fast: Xb bf16[2048][2048] @ Wt bf16[6144][2048] + bias, QKNorm+RoPE,
// scatter to Q/K [b][h][pos][d] and VT [b][h][d][pos]. 128x128, BK=64, glds.
// LDS chunk swizzle: data(row, q) at chunk c = row*8 + (q ^ (row&7)).
__global__ __launch_bounds__(256) void gemm_qkv_f(
    const ushort_t* __restrict__ Xb, const ushort_t* __restrict__ Wt,
    const float* __restrict__ bias, const float* __restrict__ qg,
    const float* __restrict__ kg, const float2* __restrict__ rtab,
    ushort_t* __restrict__ Q, ushort_t* __restrict__ K,
    ushort_t* __restrict__ VT, int stream_off)
{
  __shared__ __align__(16) union {
    struct { unsigned short a[8192]; unsigned short b[8192]; } s;
    unsigned short c[128][130];
  } L;
  __shared__ float ssq2[128][2];
  const int tid = threadIdx.x, lane = tid & 63, w = tid >> 6;
  const int quad = lane >> 4, l15 = lane & 15;
  const int wrow = (w >> 1) * 64, wcol = (w & 1) * 64;
  const int m0 = blockIdx.y * 128, n0 = blockIdx.x * 128;
  const int lsw = l15 & 7;

  f32x4 acc[4][4];
#pragma unroll
  for (int i = 0; i < 4; i++)
#pragma unroll
    for (int j = 0; j < 4; j++) acc[i][j] = (f32x4){0.f, 0.f, 0.f, 0.f};

  for (int k0 = 0; k0 < DM; k0 += 64) {
#pragma unroll
    for (int it = 0; it < 4; ++it) {
      int c = it * 256 + tid, row = c >> 3, q = (c & 7) ^ (row & 7);
      glds16(&Xb[(size_t)(m0 + row) * 2048 + k0 + q * 8], &L.s.a[c * 8]);
    }
#pragma unroll
    for (int it = 0; it < 4; ++it) {
      int c = it * 256 + tid, row = c >> 3, q = (c & 7) ^ (row & 7);
      glds16(&Wt[(size_t)(n0 + row) * 2048 + k0 + q * 8], &L.s.b[c * 8]);
    }
    __syncthreads();
#pragma unroll
    for (int h = 0; h < 2; ++h) {
      int sq = ((h * 4 + quad) ^ lsw) * 8;
      bf16x8 af[4], bfr[4];
#pragma unroll
      for (int mt = 0; mt < 4; mt++)
        af[mt] = *reinterpret_cast<const bf16x8*>(&L.s.a[(wrow + mt * 16 + l15) * 64 + sq]);
#pragma unroll
      for (int nt = 0; nt < 4; nt++)
        bfr[nt] = *reinterpret_cast<const bf16x8*>(&L.s.b[(wcol + nt * 16 + l15) * 64 + sq]);
#pragma unroll
      for (int mt = 0; mt < 4; mt++)
#pragma unroll
        for (int nt = 0; nt < 4; nt++)
          acc[mt][nt] = __builtin_amdgcn_mfma_f32_16x16x32_bf16(af[mt], bfr[nt], acc[mt][nt], 0, 0, 0);
    }
    __syncthreads();
  }

  // C -> LDS (bias added, bf16)
#pragma unroll
  for (int mt = 0; mt < 4; mt++)
#pragma unroll
    for (int nt = 0; nt < 4; nt++) {
      int col = wcol + nt * 16 + l15;
      float bv = bias[n0 + col];
#pragma unroll
      for (int i = 0; i < 4; i++)
        L.c[wrow + mt * 16 + quad * 4 + i][col] = f2bf(acc[mt][nt][i] + bv);
    }
  __syncthreads();

  const int cc = n0 >> 7, t = cc >> 4, h = cc & 15;
  const int r = tid & 127, half = tid >> 7;
  const int gr = m0 + r, b = gr >> 10;
  const int pos = stream_off + (gr & 1023);
  const int bh = b * NH + h;

  if (t == 2) {
    // VT[bh][d=j][pos] — lanes along r => pos contiguous => coalesced
    size_t vb = (size_t)bh * HD * NTOT + pos;
    for (int j = half * 64; j < half * 64 + 64; ++j)
      VT[vb + (size_t)j * NTOT] = L.c[r][j];
  } else {
    float ssq = 0.f;
    for (int j = half * 64; j < half * 64 + 64; ++j) {
      float f = bf2f(L.c[r][j]); ssq += f * f;
    }
    ssq2[r][half] = ssq;
    __syncthreads();
    float inv = rsqrtf((ssq2[r][0] + ssq2[r][1]) * (1.0f / HD) + 1e-6f);
    const float* g = (t == 0) ? qg : kg;
#pragma unroll 4
    for (int jj = 0; jj < 32; ++jj) {
      int j = half * 32 + jj;
      float xv1 = bf2f(L.c[r][j])      * inv * g[j];
      float xv2 = bf2f(L.c[r][j + 64]) * inv * g[j + 64];
      float2 cs = rtab[pos * 64 + j];
      L.c[r][j]      = f2bf(xv1 * cs.x - xv2 * cs.y);
      L.c[r][j + 64] = f2bf(xv1 * cs.y + xv2 * cs.x);
    }
    __syncthreads();
    ushort_t* dst = (t == 0) ? Q : K;
    size_t qb = ((size_t)bh * NTOT + (stream_off + (m0 & 1023))) * HD;
    COMPILER_MEM_BARRIER();
#pragma unroll
    for (int it = 0; it < 32; ++it) {
      int c = it * 256 + tid, rr = c >> 6, cl = c & 63;
      *reinterpret_cast<unsigned int*>(&dst[qb + (size_t)rr * HD + cl * 2]) =
          *reinterpret_cast<const unsigned int*>(&L.c[rr][cl * 2]);
    }
  }
}

// Flash attention fast: Q-tile 128 (4 waves x 32 rows), K-tile 64.
// Fixed-shift softmax: p = exp(s*scale - 16); sums reduced once at end.
// K & V^T staged via swizzled global_load_lds; Ps swizzled (all 2-way free).
__global__ __launch_bounds__(256) void attn_f(
    const ushort_t* __restrict__ Q, const ushort_t* __restrict__ K,
    const ushort_t* __restrict__ VT, ushort_t* __restrict__ O)
{
  __shared__ __align__(16) unsigned short Ks[64 * 128];   // [key][d] swz, 16KB
  __shared__ __align__(16) unsigned short Vs[128 * 64];   // [d][key] swz, 16KB
  __shared__ __align__(16) unsigned short Ps[128 * 64];   // [q][key] swz, 16KB

  const int tid = threadIdx.x, lane = tid & 63, w = tid >> 6;
  const int quad = lane >> 4, l15 = lane & 15;
  const int lsw = l15 & 7;
  const int b = blockIdx.z, h = blockIdx.y;
  const int q0 = blockIdx.x * 128;
  const size_t base = (size_t)(b * NH + h) * NTOT * HD;   // same count for K and VT
  const float scale = 0.088388347648318447f;
  const float SHIFT = 16.0f;

  bf16x8 qf[2][4];
#pragma unroll
  for (int mt = 0; mt < 2; mt++)
#pragma unroll
    for (int ks = 0; ks < 4; ks++)
      qf[mt][ks] = *reinterpret_cast<const bf16x8*>(
          &Q[base + (size_t)(q0 + w * 32 + mt * 16 + l15) * HD + ks * 32 + quad * 8]);

  f32x4 oacc[2][8];
#pragma unroll
  for (int mt = 0; mt < 2; mt++)
#pragma unroll
    for (int nt = 0; nt < 8; nt++) oacc[mt][nt] = (f32x4){0.f, 0.f, 0.f, 0.f};
  float lsum[2][4];
#pragma unroll
  for (int mt = 0; mt < 2; mt++)
#pragma unroll
    for (int i = 0; i < 4; i++) lsum[mt][i] = 0.f;

  for (int kt = 0; kt < NTOT / 64; ++kt) {
    // stage K: chunk c = key*16 + (q ^ (key&15))
#pragma unroll
    for (int it = 0; it < 4; ++it) {
      int c = it * 256 + tid, key = c >> 4, q = (c & 15) ^ (key & 15);
      glds16(&K[base + (size_t)(kt * 64 + key) * HD + q * 8], &Ks[c * 8]);
    }
    // stage V^T: chunk c = d*8 + (q ^ (d&7))
#pragma unroll
    for (int it = 0; it < 4; ++it) {
      int c = it * 256 + tid, d = c >> 3, q = (c & 7) ^ (d & 7);
      glds16(&VT[base + (size_t)d * NTOT + kt * 64 + q * 8], &Vs[c * 8]);
    }
    __syncthreads();

    // S = Q K^T
    f32x4 sacc[2][4];
#pragma unroll
    for (int mt = 0; mt < 2; mt++)
#pragma unroll
      for (int nt = 0; nt < 4; nt++) sacc[mt][nt] = (f32x4){0.f, 0.f, 0.f, 0.f};
#pragma unroll
    for (int ks = 0; ks < 4; ks++) {
      bf16x8 kf[4];
#pragma unroll
      for (int nt = 0; nt < 4; nt++)
        kf[nt] = *reinterpret_cast<const bf16x8*>(
            &Ks[(nt * 16 + l15) * 128 + ((ks * 4 + quad) ^ l15) * 8]);
#pragma unroll
      for (int mt = 0; mt < 2; mt++)
#pragma unroll
        for (int nt = 0; nt < 4; nt++)
          sacc[mt][nt] = __builtin_amdgcn_mfma_f32_16x16x32_bf16(qf[mt][ks], kf[nt], sacc[mt][nt], 0, 0, 0);
    }

    // fixed-shift softmax numerator; row-sum deferred (per-lane partial)
#pragma unroll
    for (int mt = 0; mt < 2; mt++)
#pragma unroll
      for (int i = 0; i < 4; i++) {
        int rowl = w * 32 + mt * 16 + quad * 4 + i;
        int rb = (quad * 4 + i) & 7;
#pragma unroll
        for (int nt = 0; nt < 4; nt++) {
          float p = __expf(fmaf(sacc[mt][nt][i], scale, -SHIFT));
          lsum[mt][i] += p;
          Ps[rowl * 64 + (((nt * 2 + (l15 >> 3)) ^ rb) * 8) + (l15 & 7)] = f2bf(p);
        }
      }
    COMPILER_MEM_BARRIER();   // Ps short-writes -> bf16x8 reads (same wave, LDS in-order)

    // O += P V
#pragma unroll
    for (int kk = 0; kk < 2; kk++) {
      bf16x8 pf[2];
#pragma unroll
      for (int mt = 0; mt < 2; mt++)
        pf[mt] = *reinterpret_cast<const bf16x8*>(
            &Ps[(w * 32 + mt * 16 + l15) * 64 + (((kk * 4 + quad) ^ lsw) * 8)]);
#pragma unroll
      for (int nt = 0; nt < 8; nt++) {
        bf16x8 vf = *reinterpret_cast<const bf16x8*>(
            &Vs[(nt * 16 + l15) * 64 + (((kk * 4 + quad) ^ lsw) * 8)]);
#pragma unroll
        for (int mt = 0; mt < 2; mt++)
          oacc[mt][nt] = __builtin_amdgcn_mfma_f32_16x16x32_bf16(pf[mt], vf, oacc[mt][nt], 0, 0, 0);
      }
    }
    __syncthreads();
  }

  // finalize: reduce row-sums across the 16 lanes of each quad-row group
#pragma unroll
  for (int mt = 0; mt < 2; mt++)
#pragma unroll
    for (int i = 0; i < 4; i++) {
      float l = lsum[mt][i];
      l += __shfl_xor(l, 1); l += __shfl_xor(l, 2);
      l += __shfl_xor(l, 4); l += __shfl_xor(l, 8);
      float linv = 1.0f / l;
      int qrow = q0 + w * 32 + mt * 16 + quad * 4 + i;
      size_t ob = ((size_t)b * NTOT + qrow) * DM + h * HD;
#pragma unroll
      for (int nt = 0; nt < 8; nt++)
        O[ob + nt * 16 + l15] = f2bf(oacc[mt][nt][i] * linv);
    }
}

// GEMM2 fast: ATT bf16 @ Woutt bf16[n][k] + bias -> fp32. Tile 128x64, BK=64.
__global__ __launch_bounds__(256) void gemm_out_f(
    const ushort_t* __restrict__ A, const ushort_t* __restrict__ Wt,
    const float* __restrict__ bias, float* __restrict__ Out, int stream_off)
{
  __shared__ __align__(16) unsigned short As[8192];  // 128x64
  __shared__ __align__(16) unsigned short Bs[4096];  // 64x64
  const int tid = threadIdx.x, lane = tid & 63, w = tid >> 6;
  const int quad = lane >> 4, l15 = lane & 15;
  const int wrow = (w & 1) * 64, wcol = (w >> 1) * 32;
  const int m0 = blockIdx.y * 128, n0 = blockIdx.x * 64;
  const int lsw = l15 & 7;

  f32x4 acc[4][2];
#pragma unroll
  for (int i = 0; i < 4; i++)
#pragma unroll
    for (int j = 0; j < 2; j++) acc[i][j] = (f32x4){0.f, 0.f, 0.f, 0.f};

  for (int k0 = 0; k0 < DM; k0 += 64) {
#pragma unroll
    for (int it = 0; it < 4; ++it) {
      int c = it * 256 + tid, row = c >> 3, q = (c & 7) ^ (row & 7);
      int gr = m0 + row;
      size_t arow = (size_t)(gr >> 10) * NTOT + stream_off + (gr & 1023);
      glds16(&A[arow * 2048 + k0 + q * 8], &As[c * 8]);
    }
#pragma unroll
    for (int it = 0; it < 2; ++it) {
      int c = it * 256 + tid, row = c >> 3, q = (c & 7) ^ (row & 7);
      glds16(&Wt[(size_t)(n0 + row) * 2048 + k0 + q * 8], &Bs[c * 8]);
    }
    __syncthreads();
#pragma unroll
    for (int h = 0; h < 2; ++h) {
      int sq = ((h * 4 + quad) ^ lsw) * 8;
      bf16x8 af[4], bfr[2];
#pragma unroll
      for (int mt = 0; mt < 4; mt++)
        af[mt] = *reinterpret_cast<const bf16x8*>(&As[(wrow + mt * 16 + l15) * 64 + sq]);
#pragma unroll
      for (int nt = 0; nt < 2; nt++)
        bfr[nt] = *reinterpret_cast<const bf16x8*>(&Bs[(wcol + nt * 16 + l15) * 64 + sq]);
#pragma unroll
      for (int mt = 0; mt < 4; mt++)
#pragma unroll
        for (int nt = 0; nt < 2; nt++)
          acc[mt][nt] = __builtin_amdgcn_mfma_f32_16x16x32_bf16(af[mt], bfr[nt], acc[mt][nt], 0, 0, 0);
    }
    __syncthreads();
  }

#pragma unroll
  for (int mt = 0; mt < 4; mt++)
#pragma unroll
    for (int nt = 0; nt < 2; nt++) {
      int col = n0 + wcol + nt * 16 + l15;
      float bv = bias[col];
#pragma unroll
      for (int i = 0; i < 4; i++) {
        int row = m0 + wrow + mt * 16 + quad * 4 + i;
        Out[(size_t)row * DM + col] = acc[mt][nt][i] + bv;
      }
    }
}

// ===========================================================================
// FALLBACK PATH (round-3, proven correct; used only if ws too small)
// ===========================================================================
union QkvLdsFb {
  struct { unsigned short a[128][40]; unsigned short b[128][40]; } s;
  unsigned short c[128][130];
};

__global__ __launch_bounds__(256) void gemm_qkv_fb(
    const float* __restrict__ X, const float* __restrict__ W,
    const float* __restrict__ bias, const float* __restrict__ qg,
    const float* __restrict__ kg,
    unsigned short* __restrict__ Q, unsigned short* __restrict__ K,
    unsigned short* __restrict__ V, int stream_off)
{
  __shared__ __align__(16) QkvLdsFb L;
  const int tid = threadIdx.x, lane = tid & 63, wv = tid >> 6;
  const int wrow = (wv >> 1) * 64, wcol = (wv & 1) * 64;
  const int quad = lane >> 4, l15 = lane & 15;
  const int m0 = blockIdx.y * 128, n0 = blockIdx.x * 128;
  f32x4 acc[4][4];
#pragma unroll
  for (int i = 0; i < 4; i++)
#pragma unroll
    for (int j = 0; j < 4; j++) acc[i][j] = (f32x4){0.f, 0.f, 0.f, 0.f};
  for (int k0 = 0; k0 < DM; k0 += 32) {
#pragma unroll
    for (int it = 0; it < 4; ++it) {
      int lin = tid + it * 256, row = lin >> 3, c4 = (lin & 7) * 4;
      float4 av = *reinterpret_cast<const float4*>(&X[(size_t)(m0 + row) * DM + k0 + c4]);
      ushort4 t4; t4.x = f2bf(av.x); t4.y = f2bf(av.y); t4.z = f2bf(av.z); t4.w = f2bf(av.w);
      *reinterpret_cast<ushort4*>(&L.s.a[row][c4]) = t4;
    }
#pragma unroll
    for (int it = 0; it < 4; ++it) {
      int lin = tid + it * 256, kr = lin >> 5, c4 = (lin & 31) * 4;
      float4 wv4 = *reinterpret_cast<const float4*>(&W[(size_t)(k0 + kr) * QKVN + n0 + c4]);
      L.s.b[c4 + 0][kr] = f2bf(wv4.x); L.s.b[c4 + 1][kr] = f2bf(wv4.y);
      L.s.b[c4 + 2][kr] = f2bf(wv4.z); L.s.b[c4 + 3][kr] = f2bf(wv4.w);
    }
    __syncthreads();
    bf16x8 af[4], bfr[4];
#pragma unroll
    for (int mt = 0; mt < 4; mt++)
      af[mt] = *reinterpret_cast<const bf16x8*>(&L.s.a[wrow + mt * 16 + l15][quad * 8]);
#pragma unroll
    for (int nt = 0; nt < 4; nt++)
      bfr[nt] = *reinterpret_cast<const bf16x8*>(&L.s.b[wcol + nt * 16 + l15][quad * 8]);
#pragma unroll
    for (int mt = 0; mt < 4; mt++)
#pragma unroll
      for (int nt = 0; nt < 4; nt++)
        acc[mt][nt] = __builtin_amdgcn_mfma_f32_16x16x32_bf16(af[mt], bfr[nt], acc[mt][nt], 0, 0, 0);
    __syncthreads();
  }
#pragma unroll
  for (int mt = 0; mt < 4; mt++)
#pragma unroll
    for (int nt = 0; nt < 4; nt++) {
      int col = wcol + nt * 16 + l15;
      float bv = bias[n0 + col];
#pragma unroll
      for (int i = 0; i < 4; i++)
        L.c[wrow + mt * 16 + quad * 4 + i][col] = f2bf(acc[mt][nt][i] + bv);
    }
  __syncthreads();
  if (tid < 128) {
    int r = tid, cc = n0 >> 7, t = cc >> 4, h = cc & 15;
    int gr = m0 + r, b = gr >> 10, n = gr & 1023, pos = stream_off + n;
    size_t base = ((size_t)(b * NH + h) * NTOT + pos) * HD;
    if (t == 2) {
      for (int j = 0; j < HD; j++) V[base + j] = L.c[r][j];
    } else {
      float ssq = 0.f;
      for (int j = 0; j < HD; j++) { float f = bf2f(L.c[r][j]); ssq += f * f; }
      float inv = rsqrtf(ssq * (1.0f / HD) + 1e-6f);
      const float* g = (t == 0) ? qg : kg;
      unsigned short* dst = (t == 0) ? Q : K;
      for (int j = 0; j < 64; j++) {
        float x1 = bf2f(L.c[r][j]) * inv * g[j];
        float x2 = bf2f(L.c[r][j + 64]) * inv * g[j + 64];
        float ang = (float)pos * exp2f(-(float)j * 0.2076205059304601f);
        float s, c; sincosf(ang, &s, &c);
        dst[base + j] = f2bf(x1 * c - x2 * s);
        dst[base + j + 64] = f2bf(x1 * s + x2 * c);
      }
    }
  }
}

__global__ __launch_bounds__(256) void attn_fb(
    const unsigned short* __restrict__ Q, const unsigned short* __restrict__ K,
    const unsigned short* __restrict__ V, unsigned short* __restrict__ O)
{
  __shared__ __align__(16) unsigned short Ks[64][136];
  __shared__ __align__(16) unsigned short Vt[128][72];
  __shared__ __align__(16) unsigned short Ps[128][72];
  const int tid = threadIdx.x, lane = tid & 63, w = tid >> 6;
  const int quad = lane >> 4, l15 = lane & 15;
  const int b = blockIdx.z, h = blockIdx.y, q0 = blockIdx.x * 128;
  const size_t base = (size_t)(b * NH + h) * NTOT * HD;
  const float scale = 0.088388347648318447f;
  bf16x8 qf[2][4];
#pragma unroll
  for (int mt = 0; mt < 2; mt++)
#pragma unroll
    for (int ks = 0; ks < 4; ks++)
      qf[mt][ks] = *reinterpret_cast<const bf16x8*>(
          &Q[base + (size_t)(q0 + w * 32 + mt * 16 + l15) * HD + ks * 32 + quad * 8]);
  f32x4 oacc[2][8];
#pragma unroll
  for (int mt = 0; mt < 2; mt++)
#pragma unroll
    for (int nt = 0; nt < 8; nt++) oacc[mt][nt] = (f32x4){0.f, 0.f, 0.f, 0.f};
  float mst[2][4], lst[2][4];
#pragma unroll
  for (int mt = 0; mt < 2; mt++)
#pragma unroll
    for (int i = 0; i < 4; i++) { mst[mt][i] = -1e30f; lst[mt][i] = 0.f; }
  for (int kt = 0; kt < NTOT / 64; ++kt) {
#pragma unroll
    for (int it = 0; it < 4; ++it) {
      int lin = tid + it * 256, kr = lin >> 4, c8 = (lin & 15) * 8;
      uint4 kv = *reinterpret_cast<const uint4*>(&K[base + (size_t)(kt * 64 + kr) * HD + c8]);
      *reinterpret_cast<uint4*>(&Ks[kr][c8]) = kv;
      uint4 vv = *reinterpret_cast<const uint4*>(&V[base + (size_t)(kt * 64 + kr) * HD + c8]);
      const unsigned short* vs = reinterpret_cast<const unsigned short*>(&vv);
#pragma unroll
      for (int j = 0; j < 8; j++) Vt[c8 + j][kr] = vs[j];
    }
    __syncthreads();
    f32x4 sacc[2][4];
#pragma unroll
    for (int mt = 0; mt < 2; mt++)
#pragma unroll
      for (int nt = 0; nt < 4; nt++) sacc[mt][nt] = (f32x4){0.f, 0.f, 0.f, 0.f};
#pragma unroll
    for (int ks = 0; ks < 4; ks++) {
      bf16x8 kf[4];
#pragma unroll
      for (int nt = 0; nt < 4; nt++)
        kf[nt] = *reinterpret_cast<const bf16x8*>(&Ks[nt * 16 + l15][ks * 32 + quad * 8]);
#pragma unroll
      for (int mt = 0; mt < 2; mt++)
#pragma unroll
        for (int nt = 0; nt < 4; nt++)
          sacc[mt][nt] = __builtin_amdgcn_mfma_f32_16x16x32_bf16(qf[mt][ks], kf[nt], sacc[mt][nt], 0, 0, 0);
    }
#pragma unroll
    for (int mt = 0; mt < 2; mt++)
#pragma unroll
      for (int i = 0; i < 4; i++) {
        float sv[4]; float rmax = -1e30f;
#pragma unroll
        for (int nt = 0; nt < 4; nt++) { sv[nt] = sacc[mt][nt][i] * scale; rmax = fmaxf(rmax, sv[nt]); }
        rmax = fmaxf(rmax, __shfl_xor(rmax, 1)); rmax = fmaxf(rmax, __shfl_xor(rmax, 2));
        rmax = fmaxf(rmax, __shfl_xor(rmax, 4)); rmax = fmaxf(rmax, __shfl_xor(rmax, 8));
        float mnew = fmaxf(mst[mt][i], rmax);
        float alpha = __expf(mst[mt][i] - mnew);
        float rsum = 0.f;
#pragma unroll
        for (int nt = 0; nt < 4; nt++) {
          float p = __expf(sv[nt] - mnew); rsum += p;
          Ps[w * 32 + mt * 16 + quad * 4 + i][nt * 16 + l15] = f2bf(p);
        }
        rsum += __shfl_xor(rsum, 1); rsum += __shfl_xor(rsum, 2);
        rsum += __shfl_xor(rsum, 4); rsum += __shfl_xor(rsum, 8);
        lst[mt][i] = lst[mt][i] * alpha + rsum; mst[mt][i] = mnew;
#pragma unroll
        for (int nt = 0; nt < 8; nt++) oacc[mt][nt][i] *= alpha;
      }
    __syncthreads();
#pragma unroll
    for (int kk = 0; kk < 2; kk++) {
      bf16x8 pf[2];
#pragma unroll
      for (int mt = 0; mt < 2; mt++)
        pf[mt] = *reinterpret_cast<const bf16x8*>(&Ps[w * 32 + mt * 16 + l15][kk * 32 + quad * 8]);
#pragma unroll
      for (int nt = 0; nt < 8; nt++) {
        bf16x8 vf = *reinterpret_cast<const bf16x8*>(&Vt[nt * 16 + l15][kk * 32 + quad * 8]);
#pragma unroll
        for (int mt = 0; mt < 2; mt++)
          oacc[mt][nt] = __builtin_amdgcn_mfma_f32_16x16x32_bf16(pf[mt], vf, oacc[mt][nt], 0, 0, 0);
      }
    }
    __syncthreads();
  }
#pragma unroll
  for (int mt = 0; mt < 2; mt++)
#pragma unroll
    for (int i = 0; i < 4; i++) {
      float linv = 1.0f / lst[mt][i];
      int qrow = q0 + w * 32 + mt * 16 + quad * 4 + i;
      size_t ob = ((size_t)b * NTOT + qrow) * DM + h * HD;
#pragma unroll
      for (int nt = 0; nt < 8; nt++)
        O[ob + nt * 16 + l15] = f2bf(oacc[mt][nt][i] * linv);
    }
}

__global__ __launch_bounds__(256) void gemm_out_fb(
    const unsigned short* __restrict__ A, const float* __restrict__ W,
    const float* __restrict__ bias, float* __restrict__ Out, int stream_off)
{
  __shared__ __align__(16) struct { unsigned short a[128][40]; unsigned short b[128][40]; } L;
  const int tid = threadIdx.x, lane = tid & 63, wv = tid >> 6;
  const int wrow = (wv >> 1) * 64, wcol = (wv & 1) * 64;
  const int quad = lane >> 4, l15 = lane & 15;
  const int m0 = blockIdx.y * 128, n0 = blockIdx.x * 128;
  f32x4 acc[4][4];
#pragma unroll
  for (int i = 0; i < 4; i++)
#pragma unroll
    for (int j = 0; j < 4; j++) acc[i][j] = (f32x4){0.f, 0.f, 0.f, 0.f};
  for (int k0 = 0; k0 < DM; k0 += 32) {
#pragma unroll
    for (int it = 0; it < 2; ++it) {
      int lin = tid + it * 256, row = lin >> 2, c8 = (lin & 3) * 8;
      int gr = m0 + row, bb = gr >> 10, n = gr & 1023;
      uint4 av = *reinterpret_cast<const uint4*>(
          &A[(size_t)(bb * NTOT + stream_off + n) * DM + k0 + c8]);
      *reinterpret_cast<uint4*>(&L.a[row][c8]) = av;
    }
#pragma unroll
    for (int it = 0; it < 4; ++it) {
      int lin = tid + it * 256, kr = lin >> 5, c4 = (lin & 31) * 4;
      float4 wv4 = *reinterpret_cast<const float4*>(&W[(size_t)(k0 + kr) * DM + n0 + c4]);
      L.b[c4 + 0][kr] = f2bf(wv4.x); L.b[c4 + 1][kr] = f2bf(wv4.y);
      L.b[c4 + 2][kr] = f2bf(wv4.z); L.b[c4 + 3][kr] = f2bf(wv4.w);
    }
    __syncthreads();
    bf16x8 af[4], bfr[4];
#pragma unroll
    for (int mt = 0; mt < 4; mt++)
      af[mt] = *reinterpret_cast<const bf16x8*>(&L.a[wrow + mt * 16 + l15][quad * 8]);
#pragma unroll
    for (int nt = 0; nt < 4; nt++)
      bfr[nt] = *reinterpret_cast<const bf16x8*>(&L.b[wcol + nt * 16 + l15][quad * 8]);
#pragma unroll
    for (int mt = 0; mt < 4; mt++)
#pragma unroll
      for (int nt = 0; nt < 4; nt++)
        acc[mt][nt] = __builtin_amdgcn_mfma_f32_16x16x32_bf16(af[mt], bfr[nt], acc[mt][nt], 0, 0, 0);
    __syncthreads();
  }
#pragma unroll
  for (int mt = 0; mt < 4; mt++)
#pragma unroll
    for (int nt = 0; nt < 4; nt++) {
      int col = wcol + nt * 16 + l15;
      float bv = bias[n0 + col];
#pragma unroll
      for (int i = 0; i < 4; i++) {
        int row = wrow + mt * 16 + quad * 4 + i;
        Out[(size_t)(m0 + row) * DM + n0 + col] = acc[mt][nt][i] + bv;
      }
    }
}

// ===========================================================================
extern "C" void kernel_launch(void* const* d_in, const int* in_sizes, int n_in,
                              void* d_out, int out_size, void* d_ws, size_t ws_size,
                              hipStream_t stream) {
  (void)in_sizes; (void)n_in; (void)out_size;
  const float* x1  = (const float*)d_in[0];
  const float* x2  = (const float*)d_in[1];
  const float* wq1 = (const float*)d_in[2];
  const float* bq1 = (const float*)d_in[3];
  const float* wq2 = (const float*)d_in[4];
  const float* bq2 = (const float*)d_in[5];
  const float* qg1 = (const float*)d_in[6];
  const float* kg1 = (const float*)d_in[7];
  const float* qg2 = (const float*)d_in[8];
  const float* kg2 = (const float*)d_in[9];
  const float* wo1 = (const float*)d_in[10];
  const float* bo1 = (const float*)d_in[11];
  const float* wo2 = (const float*)d_in[12];
  const float* bo2 = (const float*)d_in[13];
  float* out = (float*)d_out;

  // fast-path workspace layout
  unsigned char* wsb = (unsigned char*)d_ws;
  size_t o = 0;
  auto take = [&](size_t bytes) -> void* {
    void* p = wsb + o; o = (o + bytes + 255) & ~(size_t)255; return p;
  };
  ushort_t* Xb1  = (ushort_t*)take((size_t)4194304 * 2);
  ushort_t* Xb2  = (ushort_t*)take((size_t)4194304 * 2);
  ushort_t* Wq1t = (ushort_t*)take((size_t)12582912 * 2);
  ushort_t* Wq2t = (ushort_t*)take((size_t)12582912 * 2);
  ushort_t* Wo1t = (ushort_t*)take((size_t)4194304 * 2);
  ushort_t* Wo2t = (ushort_t*)take((size_t)4194304 * 2);
  float2*   rtab = (float2*)take((size_t)131072 * 8);
  ushort_t* Qf   = (ushort_t*)take((size_t)8388608 * 2);
  ushort_t* Kf   = (ushort_t*)take((size_t)8388608 * 2);
  ushort_t* VTf  = (ushort_t*)take((size_t)8388608 * 2);
  ushort_t* ATTf = (ushort_t*)take((size_t)8388608 * 2);
  const size_t need = o;

  dim3 blk(256);
  if (ws_size >= need) {
    hipLaunchKernelGGL(prep_kernel, dim3(10248), blk, 0, stream,
                       wq1, wq2, wo1, wo2, x1, x2,
                       Wq1t, Wq2t, Wo1t, Wo2t, Xb1, Xb2, rtab);
    hipLaunchKernelGGL(gemm_qkv_f, dim3(48, 16), blk, 0, stream,
                       Xb1, Wq1t, bq1, qg1, kg1, rtab, Qf, Kf, VTf, 0);
    hipLaunchKernelGGL(gemm_qkv_f, dim3(48, 16), blk, 0, stream,
                       Xb2, Wq2t, bq2, qg2, kg2, rtab, Qf, Kf, VTf, 1024);
    hipLaunchKernelGGL(attn_f, dim3(16, 16, 2), blk, 0, stream, Qf, Kf, VTf, ATTf);
    hipLaunchKernelGGL(gemm_out_f, dim3(32, 16), blk, 0, stream, ATTf, Wo1t, bo1, out, 0);
    hipLaunchKernelGGL(gemm_out_f, dim3(32, 16), blk, 0, stream,
                       ATTf, Wo2t, bo2, out + (size_t)2 * 1024 * DM, 1024);
  } else {
    const size_t QKV_ELEMS = (size_t)2 * NH * NTOT * HD;
    unsigned short* Q   = (unsigned short*)d_ws;
    unsigned short* K   = Q + QKV_ELEMS;
    unsigned short* V   = K + QKV_ELEMS;
    unsigned short* ATT = V + QKV_ELEMS;
    hipLaunchKernelGGL(gemm_qkv_fb, dim3(48, 16), blk, 0, stream, x1, wq1, bq1, qg1, kg1, Q, K, V, 0);
    hipLaunchKernelGGL(gemm_qkv_fb, dim3(48, 16), blk, 0, stream, x2, wq2, bq2, qg2, kg2, Q, K, V, 1024);
    hipLaunchKernelGGL(attn_fb, dim3(16, 16, 2), blk, 0, stream, Q, K, V, ATT);
    hipLaunchKernelGGL(gemm_out_fb, dim3(16, 16), blk, 0, stream, ATT, wo1, bo1, out, 0);
    hipLaunchKernelGGL(gemm_out_fb, dim3(16, 16), blk, 0, stream,
                       ATT, wo2, bo2, out + (size_t)2 * 1024 * DM, 1024);
  }
}

// Round 5
// 502.423 us; speedup vs baseline: 2.3232x; 1.1651x over previous
//
#include <hip/hip_runtime.h>

#define DM   2048
#define NH   16
#define HD   128
#define QKVN 6144
#define NTOT 2048

typedef __bf16 bf16x8 __attribute__((ext_vector_type(8)));
typedef float  f32x4  __attribute__((ext_vector_type(4)));
typedef unsigned short ushort_t;

__device__ __forceinline__ unsigned short f2bf(float f) {
  union { float f; unsigned u; } v; v.f = f;
  return (unsigned short)((v.u + 0x7FFFu + ((v.u >> 16) & 1u)) >> 16);
}
__device__ __forceinline__ float bf2f(unsigned short u) {
  union { unsigned u; float f; } v; v.u = ((unsigned)u) << 16;
  return v.f;
}
__device__ __forceinline__ void glds16(const void* g, void* l) {
  __builtin_amdgcn_global_load_lds(
      (const __attribute__((address_space(1))) unsigned int*)g,
      (__attribute__((address_space(3))) unsigned int*)l, 16, 0, 0);
}
#define COMPILER_MEM_BARRIER() asm volatile("" ::: "memory")

// ===========================================================================
// FAST PATH
// ===========================================================================

// prep: W transposes fp32[k][n] -> bf16[n][k]; X fp32->bf16; RoPE table.
__global__ __launch_bounds__(256) void prep_kernel(
    const float* __restrict__ wq1, const float* __restrict__ wq2,
    const float* __restrict__ wo1, const float* __restrict__ wo2,
    const float* __restrict__ x1,  const float* __restrict__ x2,
    ushort_t* __restrict__ wq1t, ushort_t* __restrict__ wq2t,
    ushort_t* __restrict__ wo1t, ushort_t* __restrict__ wo2t,
    ushort_t* __restrict__ xb1,  ushort_t* __restrict__ xb2,
    float2* __restrict__ rtab)
{
  __shared__ __align__(16) unsigned short Ls[64][72];
  const int bid = blockIdx.x, tid = threadIdx.x;
  if (bid < 8192) {
    const float* src; ushort_t* dst; int N, nb, kb;
    if (bid < 6144) {
      src = (bid < 3072) ? wq1 : wq2; dst = (bid < 3072) ? wq1t : wq2t;
      int id = bid % 3072; N = QKVN; nb = id % 96; kb = id / 96;
    } else {
      int id = bid - 6144;
      src = (id < 1024) ? wo1 : wo2; dst = (id < 1024) ? wo1t : wo2t;
      id %= 1024; N = DM; nb = id % 32; kb = id / 32;
    }
    int n0 = nb * 64, k0 = kb * 64;
#pragma unroll
    for (int it = 0; it < 4; ++it) {
      int row = (tid >> 4) + it * 16, c4 = (tid & 15) * 4;
      float4 v = *reinterpret_cast<const float4*>(&src[(size_t)(k0 + row) * N + n0 + c4]);
      Ls[c4 + 0][row] = f2bf(v.x); Ls[c4 + 1][row] = f2bf(v.y);
      Ls[c4 + 2][row] = f2bf(v.z); Ls[c4 + 3][row] = f2bf(v.w);
    }
    __syncthreads();
#pragma unroll
    for (int it = 0; it < 2; ++it) {
      int lin = tid + it * 256, r = lin >> 3, c8 = (lin & 7) * 8;
      *reinterpret_cast<uint4*>(&dst[(size_t)(n0 + r) * 2048 + k0 + c8]) =
          *reinterpret_cast<const uint4*>(&Ls[r][c8]);
    }
  } else if (bid < 10240) {
    int id = bid - 8192;
    const float* src = (id < 1024) ? x1 : x2;
    ushort_t* dst = (id < 1024) ? xb1 : xb2;
    id %= 1024;
    size_t base = (size_t)id * 4096;
#pragma unroll
    for (int it = 0; it < 4; ++it) {
      size_t i = base + (size_t)(it * 256 + tid) * 4;
      float4 v = *reinterpret_cast<const float4*>(&src[i]);
      ushort4 t; t.x = f2bf(v.x); t.y = f2bf(v.y); t.z = f2bf(v.z); t.w = f2bf(v.w);
      *reinterpret_cast<ushort4*>(&dst[i]) = t;
    }
  } else {
    int id = bid - 10240;
    int e0 = id * 16384;
    for (int i = tid; i < 16384; i += 256) {
      int e = e0 + i; int pos = e >> 6, j = e & 63;
      float ang = (float)pos * exp2f(-(float)j * 0.2076205059304601f);
      float s, c; sincosf(ang, &s, &c);
      rtab[e] = make_float2(c, s);
    }
  }
}

// GEMM1 fast (merged streams via blockIdx.z): Xb @ Wt + bias, QKNorm+RoPE,
// scatter to Q/K [b][h][pos][d] and VT [b][h][d][pos]. 128x128, BK=64, glds.
__global__ __launch_bounds__(256) void gemm_qkv_f(
    const ushort_t* __restrict__ Xb1, const ushort_t* __restrict__ Xb2,
    const ushort_t* __restrict__ Wt1, const ushort_t* __restrict__ Wt2,
    const float* __restrict__ bq1, const float* __restrict__ bq2,
    const float* __restrict__ qg1, const float* __restrict__ kg1,
    const float* __restrict__ qg2, const float* __restrict__ kg2,
    const float2* __restrict__ rtab,
    ushort_t* __restrict__ Q, ushort_t* __restrict__ K,
    ushort_t* __restrict__ VT)
{
  __shared__ __align__(16) union {
    struct { unsigned short a[8192]; unsigned short b[8192]; } s;
    unsigned short c[128][130];
  } L;
  __shared__ float ssq2[128][2];
  const int z = blockIdx.z;
  const ushort_t* Xb = z ? Xb2 : Xb1;
  const ushort_t* Wt = z ? Wt2 : Wt1;
  const float* bias = z ? bq2 : bq1;
  const float* qg = z ? qg2 : qg1;
  const float* kg = z ? kg2 : kg1;
  const int stream_off = z * 1024;

  const int tid = threadIdx.x, lane = tid & 63, w = tid >> 6;
  const int quad = lane >> 4, l15 = lane & 15;
  const int wrow = (w >> 1) * 64, wcol = (w & 1) * 64;
  const int m0 = blockIdx.y * 128, n0 = blockIdx.x * 128;
  const int lsw = l15 & 7;

  f32x4 acc[4][4];
#pragma unroll
  for (int i = 0; i < 4; i++)
#pragma unroll
    for (int j = 0; j < 4; j++) acc[i][j] = (f32x4){0.f, 0.f, 0.f, 0.f};

  for (int k0 = 0; k0 < DM; k0 += 64) {
#pragma unroll
    for (int it = 0; it < 4; ++it) {
      int c = it * 256 + tid, row = c >> 3, q = (c & 7) ^ (row & 7);
      glds16(&Xb[(size_t)(m0 + row) * 2048 + k0 + q * 8], &L.s.a[c * 8]);
    }
#pragma unroll
    for (int it = 0; it < 4; ++it) {
      int c = it * 256 + tid, row = c >> 3, q = (c & 7) ^ (row & 7);
      glds16(&Wt[(size_t)(n0 + row) * 2048 + k0 + q * 8], &L.s.b[c * 8]);
    }
    __syncthreads();
#pragma unroll
    for (int h = 0; h < 2; ++h) {
      int sq = ((h * 4 + quad) ^ lsw) * 8;
      bf16x8 af[4], bfr[4];
#pragma unroll
      for (int mt = 0; mt < 4; mt++)
        af[mt] = *reinterpret_cast<const bf16x8*>(&L.s.a[(wrow + mt * 16 + l15) * 64 + sq]);
#pragma unroll
      for (int nt = 0; nt < 4; nt++)
        bfr[nt] = *reinterpret_cast<const bf16x8*>(&L.s.b[(wcol + nt * 16 + l15) * 64 + sq]);
#pragma unroll
      for (int mt = 0; mt < 4; mt++)
#pragma unroll
        for (int nt = 0; nt < 4; nt++)
          acc[mt][nt] = __builtin_amdgcn_mfma_f32_16x16x32_bf16(af[mt], bfr[nt], acc[mt][nt], 0, 0, 0);
    }
    __syncthreads();
  }

#pragma unroll
  for (int mt = 0; mt < 4; mt++)
#pragma unroll
    for (int nt = 0; nt < 4; nt++) {
      int col = wcol + nt * 16 + l15;
      float bv = bias[n0 + col];
#pragma unroll
      for (int i = 0; i < 4; i++)
        L.c[wrow + mt * 16 + quad * 4 + i][col] = f2bf(acc[mt][nt][i] + bv);
    }
  __syncthreads();

  const int cc = n0 >> 7, t = cc >> 4, h = cc & 15;
  const int r = tid & 127, half = tid >> 7;
  const int gr = m0 + r, b = gr >> 10;
  const int pos = stream_off + (gr & 1023);
  const int bh = b * NH + h;

  if (t == 2) {
    size_t vb = (size_t)bh * HD * NTOT + pos;
    for (int j = half * 64; j < half * 64 + 64; ++j)
      VT[vb + (size_t)j * NTOT] = L.c[r][j];
  } else {
    float ssq = 0.f;
    for (int j = half * 64; j < half * 64 + 64; ++j) {
      float f = bf2f(L.c[r][j]); ssq += f * f;
    }
    ssq2[r][half] = ssq;
    __syncthreads();
    float inv = rsqrtf((ssq2[r][0] + ssq2[r][1]) * (1.0f / HD) + 1e-6f);
    const float* g = (t == 0) ? qg : kg;
#pragma unroll 4
    for (int jj = 0; jj < 32; ++jj) {
      int j = half * 32 + jj;
      float xv1 = bf2f(L.c[r][j])      * inv * g[j];
      float xv2 = bf2f(L.c[r][j + 64]) * inv * g[j + 64];
      float2 cs = rtab[pos * 64 + j];
      L.c[r][j]      = f2bf(xv1 * cs.x - xv2 * cs.y);
      L.c[r][j + 64] = f2bf(xv1 * cs.y + xv2 * cs.x);
    }
    __syncthreads();
    ushort_t* dst = (t == 0) ? Q : K;
    size_t qb = ((size_t)bh * NTOT + (stream_off + (m0 & 1023))) * HD;
    COMPILER_MEM_BARRIER();
#pragma unroll
    for (int it = 0; it < 32; ++it) {
      int c = it * 256 + tid, rr = c >> 6, cl = c & 63;
      *reinterpret_cast<unsigned int*>(&dst[qb + (size_t)rr * HD + cl * 2]) =
          *reinterpret_cast<const unsigned int*>(&L.c[rr][cl * 2]);
    }
  }
}

// Flash attention, split-K over 2 key halves (fixed-shift softmax is additive).
// blockIdx.z = b*2 + split. Writes fp32 partial O and partial row-sums.
__global__ __launch_bounds__(256) void attn_f(
    const ushort_t* __restrict__ Q, const ushort_t* __restrict__ K,
    const ushort_t* __restrict__ VT,
    float* __restrict__ Op, float* __restrict__ Lsum)
{
  __shared__ __align__(16) unsigned short Ks[64 * 128];
  __shared__ __align__(16) unsigned short Vs[128 * 64];
  __shared__ __align__(16) unsigned short Ps[128 * 64];

  const int tid = threadIdx.x, lane = tid & 63, w = tid >> 6;
  const int quad = lane >> 4, l15 = lane & 15;
  const int lsw = l15 & 7;
  const int z = blockIdx.z;
  const int b = z >> 1, split = z & 1;
  const int h = blockIdx.y;
  const int q0 = blockIdx.x * 128;
  const size_t base = (size_t)(b * NH + h) * NTOT * HD;
  const float scale = 0.088388347648318447f;
  const float SHIFT = 16.0f;

  bf16x8 qf[2][4];
#pragma unroll
  for (int mt = 0; mt < 2; mt++)
#pragma unroll
    for (int ks = 0; ks < 4; ks++)
      qf[mt][ks] = *reinterpret_cast<const bf16x8*>(
          &Q[base + (size_t)(q0 + w * 32 + mt * 16 + l15) * HD + ks * 32 + quad * 8]);

  f32x4 oacc[2][8];
#pragma unroll
  for (int mt = 0; mt < 2; mt++)
#pragma unroll
    for (int nt = 0; nt < 8; nt++) oacc[mt][nt] = (f32x4){0.f, 0.f, 0.f, 0.f};
  float lsum[2][4];
#pragma unroll
  for (int mt = 0; mt < 2; mt++)
#pragma unroll
    for (int i = 0; i < 4; i++) lsum[mt][i] = 0.f;

  const int kt0 = split * 16;
  for (int kt = kt0; kt < kt0 + 16; ++kt) {
#pragma unroll
    for (int it = 0; it < 4; ++it) {
      int c = it * 256 + tid, key = c >> 4, q = (c & 15) ^ (key & 15);
      glds16(&K[base + (size_t)(kt * 64 + key) * HD + q * 8], &Ks[c * 8]);
    }
#pragma unroll
    for (int it = 0; it < 4; ++it) {
      int c = it * 256 + tid, d = c >> 3, q = (c & 7) ^ (d & 7);
      glds16(&VT[base + (size_t)d * NTOT + kt * 64 + q * 8], &Vs[c * 8]);
    }
    __syncthreads();

    f32x4 sacc[2][4];
#pragma unroll
    for (int mt = 0; mt < 2; mt++)
#pragma unroll
      for (int nt = 0; nt < 4; nt++) sacc[mt][nt] = (f32x4){0.f, 0.f, 0.f, 0.f};
#pragma unroll
    for (int ks = 0; ks < 4; ks++) {
      bf16x8 kf[4];
#pragma unroll
      for (int nt = 0; nt < 4; nt++)
        kf[nt] = *reinterpret_cast<const bf16x8*>(
            &Ks[(nt * 16 + l15) * 128 + ((ks * 4 + quad) ^ l15) * 8]);
#pragma unroll
      for (int mt = 0; mt < 2; mt++)
#pragma unroll
        for (int nt = 0; nt < 4; nt++)
          sacc[mt][nt] = __builtin_amdgcn_mfma_f32_16x16x32_bf16(qf[mt][ks], kf[nt], sacc[mt][nt], 0, 0, 0);
    }

#pragma unroll
    for (int mt = 0; mt < 2; mt++)
#pragma unroll
      for (int i = 0; i < 4; i++) {
        int rowl = w * 32 + mt * 16 + quad * 4 + i;
        int rb = (quad * 4 + i) & 7;
#pragma unroll
        for (int nt = 0; nt < 4; nt++) {
          float p = __expf(fmaf(sacc[mt][nt][i], scale, -SHIFT));
          lsum[mt][i] += p;
          Ps[rowl * 64 + (((nt * 2 + (l15 >> 3)) ^ rb) * 8) + (l15 & 7)] = f2bf(p);
        }
      }
    COMPILER_MEM_BARRIER();

#pragma unroll
    for (int kk = 0; kk < 2; kk++) {
      bf16x8 pf[2];
#pragma unroll
      for (int mt = 0; mt < 2; mt++)
        pf[mt] = *reinterpret_cast<const bf16x8*>(
            &Ps[(w * 32 + mt * 16 + l15) * 64 + (((kk * 4 + quad) ^ lsw) * 8)]);
#pragma unroll
      for (int nt = 0; nt < 8; nt++) {
        bf16x8 vf = *reinterpret_cast<const bf16x8*>(
            &Vs[(nt * 16 + l15) * 64 + (((kk * 4 + quad) ^ lsw) * 8)]);
#pragma unroll
        for (int mt = 0; mt < 2; mt++)
          oacc[mt][nt] = __builtin_amdgcn_mfma_f32_16x16x32_bf16(pf[mt], vf, oacc[mt][nt], 0, 0, 0);
      }
    }
    __syncthreads();
  }

  // store fp32 partials: Op[(split*2+b)*NH+h][qrow][d], Lsum likewise
  const size_t pb = ((size_t)(split * 2 + b) * NH + h) * NTOT;
#pragma unroll
  for (int mt = 0; mt < 2; mt++)
#pragma unroll
    for (int i = 0; i < 4; i++) {
      float l = lsum[mt][i];
      l += __shfl_xor(l, 1); l += __shfl_xor(l, 2);
      l += __shfl_xor(l, 4); l += __shfl_xor(l, 8);
      int qrow = q0 + w * 32 + mt * 16 + quad * 4 + i;
      size_t ob = (pb + qrow) * HD;
#pragma unroll
      for (int nt = 0; nt < 8; nt++)
        Op[ob + nt * 16 + l15] = oacc[mt][nt][i];
      if (l15 == 0) Lsum[pb + qrow] = l;
    }
}

// combine: ATT[b][q][h*128+d] = (Op0+Op1)/(L0+L1), bf16
__global__ __launch_bounds__(256) void attn_combine(
    const float* __restrict__ Op, const float* __restrict__ Lsum,
    ushort_t* __restrict__ ATT)
{
  const int tid = threadIdx.x, r = tid >> 4, c8 = (tid & 15) * 8;
  const int row = blockIdx.x * 16 + r;            // 0..65535 = b*32768 + h*2048 + q
  const int q = row & 2047, h = (row >> 11) & 15, b = row >> 15;
  const size_t SPLIT = (size_t)2 * NH * NTOT;     // rows per split
  const size_t r0 = ((size_t)b * NH + h) * NTOT + q;
  const size_t r1 = r0 + SPLIT;
  float linv = 1.0f / (Lsum[r0] + Lsum[r1]);
  f32x4 a0 = *reinterpret_cast<const f32x4*>(&Op[r0 * HD + c8]);
  f32x4 a1 = *reinterpret_cast<const f32x4*>(&Op[r0 * HD + c8 + 4]);
  f32x4 b0 = *reinterpret_cast<const f32x4*>(&Op[r1 * HD + c8]);
  f32x4 b1 = *reinterpret_cast<const f32x4*>(&Op[r1 * HD + c8 + 4]);
  ushort_t o[8];
#pragma unroll
  for (int j = 0; j < 4; j++) {
    o[j]     = f2bf((a0[j] + b0[j]) * linv);
    o[j + 4] = f2bf((a1[j] + b1[j]) * linv);
  }
  *reinterpret_cast<uint4*>(&ATT[((size_t)b * NTOT + q) * DM + h * HD + c8]) =
      *reinterpret_cast<const uint4*>(o);
}

// GEMM2 fast (merged streams via blockIdx.z): ATT bf16 @ Wt bf16 + bias -> fp32
__global__ __launch_bounds__(256) void gemm_out_f(
    const ushort_t* __restrict__ A,
    const ushort_t* __restrict__ Wt1, const ushort_t* __restrict__ Wt2,
    const float* __restrict__ bo1, const float* __restrict__ bo2,
    float* __restrict__ Out)
{
  __shared__ __align__(16) unsigned short As[8192];
  __shared__ __align__(16) unsigned short Bs[4096];
  const int z = blockIdx.z;
  const ushort_t* Wt = z ? Wt2 : Wt1;
  const float* bias = z ? bo2 : bo1;
  const int stream_off = z * 1024;
  float* OutZ = Out + (size_t)z * 2 * 1024 * DM;

  const int tid = threadIdx.x, lane = tid & 63, w = tid >> 6;
  const int quad = lane >> 4, l15 = lane & 15;
  const int wrow = (w & 1) * 64, wcol = (w >> 1) * 32;
  const int m0 = blockIdx.y * 128, n0 = blockIdx.x * 64;
  const int lsw = l15 & 7;

  f32x4 acc[4][2];
#pragma unroll
  for (int i = 0; i < 4; i++)
#pragma unroll
    for (int j = 0; j < 2; j++) acc[i][j] = (f32x4){0.f, 0.f, 0.f, 0.f};

  for (int k0 = 0; k0 < DM; k0 += 64) {
#pragma unroll
    for (int it = 0; it < 4; ++it) {
      int c = it * 256 + tid, row = c >> 3, q = (c & 7) ^ (row & 7);
      int gr = m0 + row;
      size_t arow = (size_t)(gr >> 10) * NTOT + stream_off + (gr & 1023);
      glds16(&A[arow * 2048 + k0 + q * 8], &As[c * 8]);
    }
#pragma unroll
    for (int it = 0; it < 2; ++it) {
      int c = it * 256 + tid, row = c >> 3, q = (c & 7) ^ (row & 7);
      glds16(&Wt[(size_t)(n0 + row) * 2048 + k0 + q * 8], &Bs[c * 8]);
    }
    __syncthreads();
#pragma unroll
    for (int h = 0; h < 2; ++h) {
      int sq = ((h * 4 + quad) ^ lsw) * 8;
      bf16x8 af[4], bfr[2];
#pragma unroll
      for (int mt = 0; mt < 4; mt++)
        af[mt] = *reinterpret_cast<const bf16x8*>(&As[(wrow + mt * 16 + l15) * 64 + sq]);
#pragma unroll
      for (int nt = 0; nt < 2; nt++)
        bfr[nt] = *reinterpret_cast<const bf16x8*>(&Bs[(wcol + nt * 16 + l15) * 64 + sq]);
#pragma unroll
      for (int mt = 0; mt < 4; mt++)
#pragma unroll
        for (int nt = 0; nt < 2; nt++)
          acc[mt][nt] = __builtin_amdgcn_mfma_f32_16x16x32_bf16(af[mt], bfr[nt], acc[mt][nt], 0, 0, 0);
    }
    __syncthreads();
  }

#pragma unroll
  for (int mt = 0; mt < 4; mt++)
#pragma unroll
    for (int nt = 0; nt < 2; nt++) {
      int col = n0 + wcol + nt * 16 + l15;
      float bv = bias[col];
#pragma unroll
      for (int i = 0; i < 4; i++) {
        int row = m0 + wrow + mt * 16 + quad * 4 + i;
        OutZ[(size_t)row * DM + col] = acc[mt][nt][i] + bv;
      }
    }
}

// ===========================================================================
// FALLBACK PATH (round-3, proven correct; used only if ws too small)
// ===========================================================================
union QkvLdsFb {
  struct { unsigned short a[128][40]; unsigned short b[128][40]; } s;
  unsigned short c[128][130];
};

__global__ __launch_bounds__(256) void gemm_qkv_fb(
    const float* __restrict__ X, const float* __restrict__ W,
    const float* __restrict__ bias, const float* __restrict__ qg,
    const float* __restrict__ kg,
    unsigned short* __restrict__ Q, unsigned short* __restrict__ K,
    unsigned short* __restrict__ V, int stream_off)
{
  __shared__ __align__(16) QkvLdsFb L;
  const int tid = threadIdx.x, lane = tid & 63, wv = tid >> 6;
  const int wrow = (wv >> 1) * 64, wcol = (wv & 1) * 64;
  const int quad = lane >> 4, l15 = lane & 15;
  const int m0 = blockIdx.y * 128, n0 = blockIdx.x * 128;
  f32x4 acc[4][4];
#pragma unroll
  for (int i = 0; i < 4; i++)
#pragma unroll
    for (int j = 0; j < 4; j++) acc[i][j] = (f32x4){0.f, 0.f, 0.f, 0.f};
  for (int k0 = 0; k0 < DM; k0 += 32) {
#pragma unroll
    for (int it = 0; it < 4; ++it) {
      int lin = tid + it * 256, row = lin >> 3, c4 = (lin & 7) * 4;
      float4 av = *reinterpret_cast<const float4*>(&X[(size_t)(m0 + row) * DM + k0 + c4]);
      ushort4 t4; t4.x = f2bf(av.x); t4.y = f2bf(av.y); t4.z = f2bf(av.z); t4.w = f2bf(av.w);
      *reinterpret_cast<ushort4*>(&L.s.a[row][c4]) = t4;
    }
#pragma unroll
    for (int it = 0; it < 4; ++it) {
      int lin = tid + it * 256, kr = lin >> 5, c4 = (lin & 31) * 4;
      float4 wv4 = *reinterpret_cast<const float4*>(&W[(size_t)(k0 + kr) * QKVN + n0 + c4]);
      L.s.b[c4 + 0][kr] = f2bf(wv4.x); L.s.b[c4 + 1][kr] = f2bf(wv4.y);
      L.s.b[c4 + 2][kr] = f2bf(wv4.z); L.s.b[c4 + 3][kr] = f2bf(wv4.w);
    }
    __syncthreads();
    bf16x8 af[4], bfr[4];
#pragma unroll
    for (int mt = 0; mt < 4; mt++)
      af[mt] = *reinterpret_cast<const bf16x8*>(&L.s.a[wrow + mt * 16 + l15][quad * 8]);
#pragma unroll
    for (int nt = 0; nt < 4; nt++)
      bfr[nt] = *reinterpret_cast<const bf16x8*>(&L.s.b[wcol + nt * 16 + l15][quad * 8]);
#pragma unroll
    for (int mt = 0; mt < 4; mt++)
#pragma unroll
      for (int nt = 0; nt < 4; nt++)
        acc[mt][nt] = __builtin_amdgcn_mfma_f32_16x16x32_bf16(af[mt], bfr[nt], acc[mt][nt], 0, 0, 0);
    __syncthreads();
  }
#pragma unroll
  for (int mt = 0; mt < 4; mt++)
#pragma unroll
    for (int nt = 0; nt < 4; nt++) {
      int col = wcol + nt * 16 + l15;
      float bv = bias[n0 + col];
#pragma unroll
      for (int i = 0; i < 4; i++)
        L.c[wrow + mt * 16 + quad * 4 + i][col] = f2bf(acc[mt][nt][i] + bv);
    }
  __syncthreads();
  if (tid < 128) {
    int r = tid, cc = n0 >> 7, t = cc >> 4, h = cc & 15;
    int gr = m0 + r, b = gr >> 10, n = gr & 1023, pos = stream_off + n;
    size_t base = ((size_t)(b * NH + h) * NTOT + pos) * HD;
    if (t == 2) {
      for (int j = 0; j < HD; j++) V[base + j] = L.c[r][j];
    } else {
      float ssq = 0.f;
      for (int j = 0; j < HD; j++) { float f = bf2f(L.c[r][j]); ssq += f * f; }
      float inv = rsqrtf(ssq * (1.0f / HD) + 1e-6f);
      const float* g = (t == 0) ? qg : kg;
      unsigned short* dst = (t == 0) ? Q : K;
      for (int j = 0; j < 64; j++) {
        float x1 = bf2f(L.c[r][j]) * inv * g[j];
        float x2 = bf2f(L.c[r][j + 64]) * inv * g[j + 64];
        float ang = (float)pos * exp2f(-(float)j * 0.2076205059304601f);
        float s, c; sincosf(ang, &s, &c);
        dst[base + j] = f2bf(x1 * c - x2 * s);
        dst[base + j + 64] = f2bf(x1 * s + x2 * c);
      }
    }
  }
}

__global__ __launch_bounds__(256) void attn_fb(
    const unsigned short* __restrict__ Q, const unsigned short* __restrict__ K,
    const unsigned short* __restrict__ V, unsigned short* __restrict__ O)
{
  __shared__ __align__(16) unsigned short Ks[64][136];
  __shared__ __align__(16) unsigned short Vt[128][72];
  __shared__ __align__(16) unsigned short Ps[128][72];
  const int tid = threadIdx.x, lane = tid & 63, w = tid >> 6;
  const int quad = lane >> 4, l15 = lane & 15;
  const int b = blockIdx.z, h = blockIdx.y, q0 = blockIdx.x * 128;
  const size_t base = (size_t)(b * NH + h) * NTOT * HD;
  const float scale = 0.088388347648318447f;
  bf16x8 qf[2][4];
#pragma unroll
  for (int mt = 0; mt < 2; mt++)
#pragma unroll
    for (int ks = 0; ks < 4; ks++)
      qf[mt][ks] = *reinterpret_cast<const bf16x8*>(
          &Q[base + (size_t)(q0 + w * 32 + mt * 16 + l15) * HD + ks * 32 + quad * 8]);
  f32x4 oacc[2][8];
#pragma unroll
  for (int mt = 0; mt < 2; mt++)
#pragma unroll
    for (int nt = 0; nt < 8; nt++) oacc[mt][nt] = (f32x4){0.f, 0.f, 0.f, 0.f};
  float mst[2][4], lst[2][4];
#pragma unroll
  for (int mt = 0; mt < 2; mt++)
#pragma unroll
    for (int i = 0; i < 4; i++) { mst[mt][i] = -1e30f; lst[mt][i] = 0.f; }
  for (int kt = 0; kt < NTOT / 64; ++kt) {
#pragma unroll
    for (int it = 0; it < 4; ++it) {
      int lin = tid + it * 256, kr = lin >> 4, c8 = (lin & 15) * 8;
      uint4 kv = *reinterpret_cast<const uint4*>(&K[base + (size_t)(kt * 64 + kr) * HD + c8]);
      *reinterpret_cast<uint4*>(&Ks[kr][c8]) = kv;
      uint4 vv = *reinterpret_cast<const uint4*>(&V[base + (size_t)(kt * 64 + kr) * HD + c8]);
      const unsigned short* vs = reinterpret_cast<const unsigned short*>(&vv);
#pragma unroll
      for (int j = 0; j < 8; j++) Vt[c8 + j][kr] = vs[j];
    }
    __syncthreads();
    f32x4 sacc[2][4];
#pragma unroll
    for (int mt = 0; mt < 2; mt++)
#pragma unroll
      for (int nt = 0; nt < 4; nt++) sacc[mt][nt] = (f32x4){0.f, 0.f, 0.f, 0.f};
#pragma unroll
    for (int ks = 0; ks < 4; ks++) {
      bf16x8 kf[4];
#pragma unroll
      for (int nt = 0; nt < 4; nt++)
        kf[nt] = *reinterpret_cast<const bf16x8*>(&Ks[nt * 16 + l15][ks * 32 + quad * 8]);
#pragma unroll
      for (int mt = 0; mt < 2; mt++)
#pragma unroll
        for (int nt = 0; nt < 4; nt++)
          sacc[mt][nt] = __builtin_amdgcn_mfma_f32_16x16x32_bf16(qf[mt][ks], kf[nt], sacc[mt][nt], 0, 0, 0);
    }
#pragma unroll
    for (int mt = 0; mt < 2; mt++)
#pragma unroll
      for (int i = 0; i < 4; i++) {
        float sv[4]; float rmax = -1e30f;
#pragma unroll
        for (int nt = 0; nt < 4; nt++) { sv[nt] = sacc[mt][nt][i] * scale; rmax = fmaxf(rmax, sv[nt]); }
        rmax = fmaxf(rmax, __shfl_xor(rmax, 1)); rmax = fmaxf(rmax, __shfl_xor(rmax, 2));
        rmax = fmaxf(rmax, __shfl_xor(rmax, 4)); rmax = fmaxf(rmax, __shfl_xor(rmax, 8));
        float mnew = fmaxf(mst[mt][i], rmax);
        float alpha = __expf(mst[mt][i] - mnew);
        float rsum = 0.f;
#pragma unroll
        for (int nt = 0; nt < 4; nt++) {
          float p = __expf(sv[nt] - mnew); rsum += p;
          Ps[w * 32 + mt * 16 + quad * 4 + i][nt * 16 + l15] = f2bf(p);
        }
        rsum += __shfl_xor(rsum, 1); rsum += __shfl_xor(rsum, 2);
        rsum += __shfl_xor(rsum, 4); rsum += __shfl_xor(rsum, 8);
        lst[mt][i] = lst[mt][i] * alpha + rsum; mst[mt][i] = mnew;
#pragma unroll
        for (int nt = 0; nt < 8; nt++) oacc[mt][nt][i] *= alpha;
      }
    __syncthreads();
#pragma unroll
    for (int kk = 0; kk < 2; kk++) {
      bf16x8 pf[2];
#pragma unroll
      for (int mt = 0; mt < 2; mt++)
        pf[mt] = *reinterpret_cast<const bf16x8*>(&Ps[w * 32 + mt * 16 + l15][kk * 32 + quad * 8]);
#pragma unroll
      for (int nt = 0; nt < 8; nt++) {
        bf16x8 vf = *reinterpret_cast<const bf16x8*>(&Vt[nt * 16 + l15][kk * 32 + quad * 8]);
#pragma unroll
        for (int mt = 0; mt < 2; mt++)
          oacc[mt][nt] = __builtin_amdgcn_mfma_f32_16x16x32_bf16(pf[mt], vf, oacc[mt][nt], 0, 0, 0);
      }
    }
    __syncthreads();
  }
#pragma unroll
  for (int mt = 0; mt < 2; mt++)
#pragma unroll
    for (int i = 0; i < 4; i++) {
      float linv = 1.0f / lst[mt][i];
      int qrow = q0 + w * 32 + mt * 16 + quad * 4 + i;
      size_t ob = ((size_t)b * NTOT + qrow) * DM + h * HD;
#pragma unroll
      for (int nt = 0; nt < 8; nt++)
        O[ob + nt * 16 + l15] = f2bf(oacc[mt][nt][i] * linv);
    }
}

__global__ __launch_bounds__(256) void gemm_out_fb(
    const unsigned short* __restrict__ A, const float* __restrict__ W,
    const float* __restrict__ bias, float* __restrict__ Out, int stream_off)
{
  __shared__ __align__(16) struct { unsigned short a[128][40]; unsigned short b[128][40]; } L;
  const int tid = threadIdx.x, lane = tid & 63, wv = tid >> 6;
  const int wrow = (wv >> 1) * 64, wcol = (wv & 1) * 64;
  const int quad = lane >> 4, l15 = lane & 15;
  const int m0 = blockIdx.y * 128, n0 = blockIdx.x * 128;
  f32x4 acc[4][4];
#pragma unroll
  for (int i = 0; i < 4; i++)
#pragma unroll
    for (int j = 0; j < 4; j++) acc[i][j] = (f32x4){0.f, 0.f, 0.f, 0.f};
  for (int k0 = 0; k0 < DM; k0 += 32) {
#pragma unroll
    for (int it = 0; it < 2; ++it) {
      int lin = tid + it * 256, row = lin >> 2, c8 = (lin & 3) * 8;
      int gr = m0 + row, bb = gr >> 10, n = gr & 1023;
      uint4 av = *reinterpret_cast<const uint4*>(
          &A[(size_t)(bb * NTOT + stream_off + n) * DM + k0 + c8]);
      *reinterpret_cast<uint4*>(&L.a[row][c8]) = av;
    }
#pragma unroll
    for (int it = 0; it < 4; ++it) {
      int lin = tid + it * 256, kr = lin >> 5, c4 = (lin & 31) * 4;
      float4 wv4 = *reinterpret_cast<const float4*>(&W[(size_t)(k0 + kr) * DM + n0 + c4]);
      L.b[c4 + 0][kr] = f2bf(wv4.x); L.b[c4 + 1][kr] = f2bf(wv4.y);
      L.b[c4 + 2][kr] = f2bf(wv4.z); L.b[c4 + 3][kr] = f2bf(wv4.w);
    }
    __syncthreads();
    bf16x8 af[4], bfr[4];
#pragma unroll
    for (int mt = 0; mt < 4; mt++)
      af[mt] = *reinterpret_cast<const bf16x8*>(&L.a[wrow + mt * 16 + l15][quad * 8]);
#pragma unroll
    for (int nt = 0; nt < 4; nt++)
      bfr[nt] = *reinterpret_cast<const bf16x8*>(&L.b[wcol + nt * 16 + l15][quad * 8]);
#pragma unroll
    for (int mt = 0; mt < 4; mt++)
#pragma unroll
      for (int nt = 0; nt < 4; nt++)
        acc[mt][nt] = __builtin_amdgcn_mfma_f32_16x16x32_bf16(af[mt], bfr[nt], acc[mt][nt], 0, 0, 0);
    __syncthreads();
  }
#pragma unroll
  for (int mt = 0; mt < 4; mt++)
#pragma unroll
    for (int nt = 0; nt < 4; nt++) {
      int col = wcol + nt * 16 + l15;
      float bv = bias[n0 + col];
#pragma unroll
      for (int i = 0; i < 4; i++) {
        int row = wrow + mt * 16 + quad * 4 + i;
        Out[(size_t)(m0 + row) * DM + n0 + col] = acc[mt][nt][i] + bv;
      }
    }
}

// ===========================================================================
extern "C" void kernel_launch(void* const* d_in, const int* in_sizes, int n_in,
                              void* d_out, int out_size, void* d_ws, size_t ws_size,
                              hipStream_t stream) {
  (void)in_sizes; (void)n_in; (void)out_size;
  const float* x1  = (const float*)d_in[0];
  const float* x2  = (const float*)d_in[1];
  const float* wq1 = (const float*)d_in[2];
  const float* bq1 = (const float*)d_in[3];
  const float* wq2 = (const float*)d_in[4];
  const float* bq2 = (const float*)d_in[5];
  const float* qg1 = (const float*)d_in[6];
  const float* kg1 = (const float*)d_in[7];
  const float* qg2 = (const float*)d_in[8];
  const float* kg2 = (const float*)d_in[9];
  const float* wo1 = (const float*)d_in[10];
  const float* bo1 = (const float*)d_in[11];
  const float* wo2 = (const float*)d_in[12];
  const float* bo2 = (const float*)d_in[13];
  float* out = (float*)d_out;

  unsigned char* wsb = (unsigned char*)d_ws;
  size_t o = 0;
  auto take = [&](size_t bytes) -> void* {
    void* p = wsb + o; o = (o + bytes + 255) & ~(size_t)255; return p;
  };
  ushort_t* Xb1  = (ushort_t*)take((size_t)4194304 * 2);
  ushort_t* Xb2  = (ushort_t*)take((size_t)4194304 * 2);
  ushort_t* Wq1t = (ushort_t*)take((size_t)12582912 * 2);
  ushort_t* Wq2t = (ushort_t*)take((size_t)12582912 * 2);
  ushort_t* Wo1t = (ushort_t*)take((size_t)4194304 * 2);
  ushort_t* Wo2t = (ushort_t*)take((size_t)4194304 * 2);
  float2*   rtab = (float2*)take((size_t)131072 * 8);
  ushort_t* Qf   = (ushort_t*)take((size_t)8388608 * 2);
  ushort_t* Kf   = (ushort_t*)take((size_t)8388608 * 2);
  ushort_t* VTf  = (ushort_t*)take((size_t)8388608 * 2);
  ushort_t* ATTf = (ushort_t*)take((size_t)8388608 * 2);
  const size_t need = o;
  // split-K attention partials overlay dead regions (all < rtab offset):
  // Op: 64 MB fp32 over Xb1..Wq2t (contiguous, sizes are 256-multiples)
  float* Op   = (float*)Xb1;
  float* Lsum = (float*)rtab;   // 512 KB over 1 MB rtab (dead after gemm_qkv)

  dim3 blk(256);
  if (ws_size >= need) {
    hipLaunchKernelGGL(prep_kernel, dim3(10248), blk, 0, stream,
                       wq1, wq2, wo1, wo2, x1, x2,
                       Wq1t, Wq2t, Wo1t, Wo2t, Xb1, Xb2, rtab);
    hipLaunchKernelGGL(gemm_qkv_f, dim3(48, 16, 2), blk, 0, stream,
                       Xb1, Xb2, Wq1t, Wq2t, bq1, bq2, qg1, kg1, qg2, kg2,
                       rtab, Qf, Kf, VTf);
    hipLaunchKernelGGL(attn_f, dim3(16, 16, 4), blk, 0, stream, Qf, Kf, VTf, Op, Lsum);
    hipLaunchKernelGGL(attn_combine, dim3(4096), blk, 0, stream, Op, Lsum, ATTf);
    hipLaunchKernelGGL(gemm_out_f, dim3(32, 16, 2), blk, 0, stream,
                       ATTf, Wo1t, Wo2t, bo1, bo2, out);
  } else {
    const size_t QKV_ELEMS = (size_t)2 * NH * NTOT * HD;
    unsigned short* Q   = (unsigned short*)d_ws;
    unsigned short* K   = Q + QKV_ELEMS;
    unsigned short* V   = K + QKV_ELEMS;
    unsigned short* ATT = V + QKV_ELEMS;
    hipLaunchKernelGGL(gemm_qkv_fb, dim3(48, 16), blk, 0, stream, x1, wq1, bq1, qg1, kg1, Q, K, V, 0);
    hipLaunchKernelGGL(gemm_qkv_fb, dim3(48, 16), blk, 0, stream, x2, wq2, bq2, qg2, kg2, Q, K, V, 1024);
    hipLaunchKernelGGL(attn_fb, dim3(16, 16, 2), blk, 0, stream, Q, K, V, ATT);
    hipLaunchKernelGGL(gemm_out_fb, dim3(16, 16), blk, 0, stream, ATT, wo1, bo1, out, 0);
    hipLaunchKernelGGL(gemm_out_fb, dim3(16, 16), blk, 0, stream,
                       ATT, wo2, bo2, out + (size_t)2 * 1024 * DM, 1024);
  }
}